// Round 6
// baseline (109.216 us; speedup 1.0000x reference)
//
#include <hip/hip_runtime.h>

// ContrastiveEmbeddingLoss, N=8192, D=128, C=100, margin=1.
// loss = [ sum_{y_i!=y_j} d_ij + N*margin + sum_{same,i!=j} max(margin-d_ij,0) ] / N^2
//   dissim = 2*sum_c SQ_c*(N - n_c) - 2*||S||^2 + 2*SSsum
//     SQ_c = sum_{i in c}||x_i||^2,  S = sum_i x_i,  SSsum = sum_c sum_{a,b in c} x_a.x_b
// Only same-class pairs (~N^2/100) need explicit d -> per-class fp16 MFMA Gram.
//
// v6: 3 nodes, list built ONCE in a single block with LDS-only atomics.
// History: v3/v4 (fused per-row global placement atomics in scan) = +18us;
// v5 (list rebuilt in all 800 gram blocks) = +9us. The 97us baseline split
// the list build into a cheap dedicated pass - keep that, but shrink it:
// one block, LDS histogram, no global atomics, and it also zeroes the 4KB
// accumulator region (absorbing the memset node).
//   build (1 blk: zero region + rank/cnt via LDS histogram)
//   -> scan (baseline body: coalesced pass, [c][slot] placement stores)
//   -> gram (baseline body + Dterm; last block finalizes via done-counter)

#define N_ROWS 8192
#define DIM    128
#define NCLS   100
#define CAP    224            // Binom(8192,0.01): mean 82, sd 9 -> +15 sigma
#define SCB    1024           // scan blocks (8 rows each)
#define GBPC   8              // gram blocks per class
#define GRAMB  (NCLS * GBPC)  // 800
#define NREP   8              // atomic replication for Scol
#define ZWORDS (NREP * DIM + 3) // Scol8 + Hsum + SSsum + done = 1027

typedef _Float16 half8  __attribute__((ext_vector_type(8)));
typedef _Float16 half4v __attribute__((ext_vector_type(4)));
typedef float    float4v __attribute__((ext_vector_type(4)));

// ---------------- Kernel 0: one-block placement + zeroing ------------------
// rank[r] = slot of row r within its class (LDS histogram, block-scope
// atomics only), cnt[c] = class size. Also zeroes the accumulator region.
__global__ __launch_bounds__(256) void build_kernel(
    const int* __restrict__ y, int* __restrict__ rank, int* __restrict__ cnt,
    int* __restrict__ zreg)
{
    const int tid = threadIdx.x;
    __shared__ int lcnt[NCLS];
    if (tid < NCLS) lcnt[tid] = 0;
    #pragma unroll
    for (int i = tid; i < ZWORDS; i += 256) zreg[i] = 0;
    __syncthreads();
    #pragma unroll
    for (int it = 0; it < N_ROWS / 256; ++it) {      // 32 iterations
        const int r = it * 256 + tid;                // coalesced y/rank
        rank[r] = atomicAdd(&lcnt[y[r]], 1);         // LDS atomic (block)
    }
    __syncthreads();
    if (tid < NCLS) cnt[tid] = lcnt[tid];
}

// ---------------- Kernel 1: one coalesced pass over x ----------------------
// gh[c][slot][128] fp16, sqg[c][slot], Scol8[NREP][128]. Placement is a
// plain rank[r] load (no RMW round-trip on the store path - baseline-proven).
__global__ __launch_bounds__(256) void scan_kernel(
    const float* __restrict__ x, const int* __restrict__ y,
    const int* __restrict__ rank,
    _Float16* __restrict__ gh, float* __restrict__ sqg,
    float* __restrict__ Scol8)
{
    const int b = blockIdx.x, tid = threadIdx.x;
    const int l = tid & 31, g = tid >> 5;            // 32 lanes/row, 8 rows/blk
    const int r = b * 8 + g;
    const int rep = b & (NREP - 1);
    const float4* x4 = (const float4*)x;
    __shared__ float4 colred[256];

    float4 v = x4[r * 32 + l];                       // fully coalesced
    float s = v.x*v.x + v.y*v.y + v.z*v.z + v.w*v.w;
    s += __shfl_xor(s, 1);  s += __shfl_xor(s, 2);  s += __shfl_xor(s, 4);
    s += __shfl_xor(s, 8);  s += __shfl_xor(s, 16);  // row sqnorm
    const int c = y[r];                              // uniform per group
    const int p = rank[r];                           // precomputed placement
    if (p < CAP) {                                   // never false in practice
        half4v h;
        h[0] = (_Float16)v.x; h[1] = (_Float16)v.y;
        h[2] = (_Float16)v.z; h[3] = (_Float16)v.w;
        *(half4v*)(gh + (size_t)(c * CAP + p) * DIM + l * 4) = h;
        if (l == 0) sqg[c * CAP + p] = s;
    }

    colred[tid] = v;
    __syncthreads();
    if (tid < 32) {
        float4 a = colred[tid];
        #pragma unroll
        for (int gg = 1; gg < 8; ++gg) {
            float4 t = colred[tid + 32 * gg];
            a.x += t.x; a.y += t.y; a.z += t.z; a.w += t.w;
        }
        float* dst = Scol8 + rep * DIM;              // ~128-way contention
        atomicAdd(&dst[4 * tid + 0], a.x);
        atomicAdd(&dst[4 * tid + 1], a.y);
        atomicAdd(&dst[4 * tid + 2], a.z);
        atomicAdd(&dst[4 * tid + 3], a.w);
    }
}

// ------- Kernel 2: per-class MFMA Gram hinge (8 blocks/class) + finalize ----
__global__ __launch_bounds__(256) void gram_kernel(
    const _Float16* __restrict__ gh, const float* __restrict__ sqg,
    const int* __restrict__ cnt,
    const float* __restrict__ Scol8,
    float* __restrict__ Hsum, float* __restrict__ SSsum,
    double* __restrict__ Dterm,
    int* __restrict__ done, float* __restrict__ out)
{
    const int c = blockIdx.x >> 3, qq = blockIdx.x & 7, tid = threadIdx.x;
    __shared__ float wred[12];
    __shared__ int   lastFlag;

    const int mtrue = cnt[c];
    const int m = mtrue < CAP ? mtrue : CAP;
    const int ntiles = (m + 15) >> 4;
    const int ntp = ntiles * (ntiles + 1) / 2;       // ~21 for m~82

    const int wave = tid >> 6, lane = tid & 63;
    const int lr = lane & 15, q = lane >> 4;
    float hacc = 0.f, dsum = 0.f;
    const _Float16* base = gh + (size_t)c * CAP * DIM;
    const float* sqb_ = sqg + c * CAP;

    // qq==0 block also gathers SQ_c = sum sqg[c][0..m) (contiguous, m<256)
    float qv = (qq == 0 && tid < m) ? sqb_[tid] : 0.f;

    // 32 waves/class: almost always <=1 tile-pair per wave.
    for (int tp = qq * 4 + wave; tp < ntp; tp += 32) {
        int ta = 0, rem = tp;
        while (rem >= ntiles - ta) { rem -= ntiles - ta; ++ta; }
        const int tb = ta + rem;
        // Pad rows hold benign fp16 poison (no NaN/Inf); outputs gated below.
        const half8* ap = (const half8*)(base + (ta * 16 + lr) * DIM + q * 8);
        const half8* bp = (const half8*)(base + (tb * 16 + lr) * DIM + q * 8);
        float4v acc = {0.f, 0.f, 0.f, 0.f};
        #pragma unroll
        for (int kb = 0; kb < 4; ++kb)               // +32 halves per K block
            acc = __builtin_amdgcn_mfma_f32_16x16x32_f16(ap[kb * 4], bp[kb * 4], acc, 0, 0, 0);
        const float w = (ta == tb) ? 1.f : 2.f;
        const int bb = tb * 16 + lr;                 // C/D col = lane & 15
        const float sqb = (bb < m) ? sqb_[bb] : 0.f;
        #pragma unroll
        for (int i = 0; i < 4; ++i) {
            const int a = ta * 16 + q * 4 + i;       // C/D row = quad*4 + reg
            if (a < m && bb < m) {
                const float dot = acc[i];
                dsum += w * dot;                     // includes diagonal a==bb
                if (a != bb) {
                    float d = fmaxf(sqb_[a] + sqb - 2.f * dot, 0.f);
                    hacc += w * fmaxf(1.f - d, 0.f);
                }
            }
        }
    }
    #pragma unroll
    for (int off = 32; off > 0; off >>= 1) {
        hacc += __shfl_xor(hacc, off);
        dsum += __shfl_xor(dsum, off);
        qv   += __shfl_xor(qv,   off);
    }
    if (lane == 0) { wred[wave] = hacc; wred[4 + wave] = dsum; wred[8 + wave] = qv; }
    __syncthreads();
    if (tid == 0) {
        float h = wred[0] + wred[1] + wred[2] + wred[3];
        float d = wred[4] + wred[5] + wred[6] + wred[7];
        if (qq == 0) {                               // class dissim term
            float qs = wred[8] + wred[9] + wred[10] + wred[11];
            Dterm[c] = 2.0 * (double)qs * ((double)N_ROWS - (double)mtrue);
        }
        if (h != 0.f) atomicAdd(Hsum, h);
        if (d != 0.f) atomicAdd(SSsum, d);
        __threadfence();                             // release before counting
        int p = atomicAdd(done, 1);
        lastFlag = (p == GRAMB - 1);
    }
    __syncthreads();
    if (!lastFlag) return;

    // ---------------- fused finalize (last-arriving block only) ------------
    __threadfence();                                 // acquire others' results
    const double Nf = (double)N_ROWS;
    double contrib = 0.0;
    if (tid < DIM) {                                 // -2 ||S||^2
        float sc = 0.f;
        #pragma unroll
        for (int k = 0; k < NREP; ++k) sc += Scol8[k * DIM + tid];
        contrib -= 2.0 * (double)sc * (double)sc;
    }
    if (tid < NCLS) contrib += Dterm[tid];           // 2 SQ_c (N - n_c)
    if (tid == 0) {
        float H  = __hip_atomic_load(Hsum,  __ATOMIC_RELAXED, __HIP_MEMORY_SCOPE_AGENT);
        float SS = __hip_atomic_load(SSsum, __ATOMIC_RELAXED, __HIP_MEMORY_SCOPE_AGENT);
        contrib += 2.0 * (double)SS + (double)H + Nf * 1.0 /* N*margin */;
    }
    __shared__ double dred[256];
    dred[tid] = contrib;
    __syncthreads();
    for (int s = 128; s > 0; s >>= 1) {
        if (tid < s) dred[tid] += dred[tid + s];
        __syncthreads();
    }
    if (tid == 0) out[0] = (float)(dred[0] / (Nf * Nf));
}

extern "C" void kernel_launch(void* const* d_in, const int* in_sizes, int n_in,
                              void* d_out, int out_size, void* d_ws, size_t ws_size,
                              hipStream_t stream) {
    const float* x = (const float*)d_in[0];
    const int*   y = (const int*)d_in[1];

    _Float16* gh = (_Float16*)d_ws;                         // 100*224*128 fp16 = 5.73 MB
    float* sqg   = (float*)(gh + (size_t)NCLS * CAP * DIM); // 100*224
    int*   rank  = (int*)(sqg + NCLS * CAP);                // 8192
    int*   cnt   = rank + N_ROWS;                           // 100
    // ---- zero region (zeroed by build_kernel, ZWORDS = 1027 words): ----
    float* Scol8 = (float*)(cnt + NCLS);       // NREP*128
    float* Hsum  = Scol8 + NREP * DIM;         // 1
    float* SSsum = Hsum + 1;                   // 1
    int*   done  = (int*)(SSsum + 1);          // 1
    // ---- always-written region (8B-aligned via +1 pad word): ----
    double* Dterm = (double*)(done + 2);       // 100 doubles

    build_kernel<<<1,     256, 0, stream>>>(y, rank, cnt, (int*)Scol8);
    scan_kernel<<<SCB,    256, 0, stream>>>(x, y, rank, gh, sqg, Scol8);
    gram_kernel<<<GRAMB,  256, 0, stream>>>(gh, sqg, cnt, Scol8,
                                            Hsum, SSsum, Dterm, done,
                                            (float*)d_out);
}

// Round 7
// 99.354 us; speedup vs baseline: 1.0993x; 1.0993x over previous
//
#include <hip/hip_runtime.h>

// ContrastiveEmbeddingLoss, N=8192, D=128, C=100, margin=1.
// loss = [ sum_{y_i!=y_j} d_ij + N*margin + sum_{same,i!=j} max(margin-d_ij,0) ] / N^2
//   dissim = 2*sum_c SQ_c*(N - n_c) - 2*||S||^2 + 2*SSsum
//     SQ_c = sum_{i in c}||x_i||^2,  S = sum_i x_i,  SSsum = sum_c sum_{a,b in c} x_a.x_b
// Only same-class pairs (~N^2/100) need explicit d -> per-class fp16 MFMA Gram.
//
// v7 = EXACT round-0 baseline (97.0 us, harness-verified), restored after the
// structural search lost in every direction:
//   v2 coop fusion        243 us  (grid.sync ~155us on this ROCm build)
//   v3 fused placement    115 us  (8192 contended cross-XCD atomics in scan)
//   v4 row-store + idx    115 us  (same atomics; dependent-store theory falsified)
//   v5 list-in-gram       106 us  (800x redundant ballot list builds)
//   v6 1-block build      109 us  (single-CU latency-serial histogram)
// The 4-node split is a narrow optimum: parallel rank pass (no dependent
// stores), pure streaming scan, done-counter gram finalize. Remaining time
// is harness poison fills (2x 256MiB @ ~41us, ~81% HBM peak) + ~15us of
// dispatches -> external floor.
//
// 4 graph nodes: memset(7.7KB) -> rank (LDS-histogram ranking, no dependent
// stores) -> scan (coalesced pass, placement precomputed -> full MLP) ->
// gram (800 blocks, <=1 tile-pair/wave; last block finalizes via done-counter).

#define N_ROWS 8192
#define DIM    128
#define NCLS   100
#define CAP    224            // Binom(8192,0.01): mean 82, sd 9 -> +15 sigma
#define RB     32             // rank blocks (256 rows each)
#define SCB    1024           // scan blocks (8 rows each)
#define GBPC   8              // gram blocks per class
#define GRAMB  (NCLS * GBPC)  // 800
#define NREP   8              // atomic replication for Scol/SQc

typedef _Float16 half8  __attribute__((ext_vector_type(8)));
typedef _Float16 half4v __attribute__((ext_vector_type(4)));
typedef float    float4v __attribute__((ext_vector_type(4)));

// ---------------- Kernel 0: per-row class rank, no atomic->store chains ----
__global__ __launch_bounds__(256) void rank_kernel(
    const int* __restrict__ y, int* __restrict__ cnt, int* __restrict__ rank)
{
    const int tid = threadIdx.x, r = blockIdx.x * 256 + tid;
    __shared__ int lcnt[NCLS], lbase[NCLS];
    if (tid < NCLS) lcnt[tid] = 0;
    __syncthreads();
    const int c = y[r];
    const int intra = atomicAdd(&lcnt[c], 1);        // LDS atomic (block scope)
    __syncthreads();
    if (tid < NCLS && lcnt[tid] > 0)
        lbase[tid] = atomicAdd(&cnt[tid], lcnt[tid]); // 100x32 global atomics
    __syncthreads();
    rank[r] = lbase[c] + intra;
}

// ---------------- Kernel 1: one coalesced pass over x, all stores free ------
// gh[c][rank][128] fp16 rows, sqg[c][rank], Scol8[NREP][128], SQc8[NREP][100].
__global__ __launch_bounds__(256) void scan_kernel(
    const float* __restrict__ x, const int* __restrict__ y,
    const int* __restrict__ rank,
    _Float16* __restrict__ gh, float* __restrict__ sqg,
    float* __restrict__ Scol8, float* __restrict__ SQc8)
{
    const int b = blockIdx.x, tid = threadIdx.x;
    const int l = tid & 31, g = tid >> 5;            // 32 lanes/row, 8 rows/blk
    const int r = b * 8 + g;
    const int rep = b & (NREP - 1);
    const float4* x4 = (const float4*)x;
    __shared__ float4 colred[256];

    float4 v = x4[r * 32 + l];                       // fully coalesced
    float s = v.x*v.x + v.y*v.y + v.z*v.z + v.w*v.w;
    s += __shfl_xor(s, 1);  s += __shfl_xor(s, 2);  s += __shfl_xor(s, 4);
    s += __shfl_xor(s, 8);  s += __shfl_xor(s, 16);  // row sqnorm
    const int c = y[r];                              // uniform per group
    const int p = rank[r];                           // precomputed placement
    if (p < CAP) {                                   // never false in practice
        half4v h;
        h[0] = (_Float16)v.x; h[1] = (_Float16)v.y;
        h[2] = (_Float16)v.z; h[3] = (_Float16)v.w;
        *(half4v*)(gh + (size_t)(c * CAP + p) * DIM + l * 4) = h;
        if (l == 0) sqg[c * CAP + p] = s;
    }
    if (l == 0) atomicAdd(&SQc8[rep * NCLS + c], s); // ~10-way contention

    colred[tid] = v;
    __syncthreads();
    if (tid < 32) {
        float4 a = colred[tid];
        #pragma unroll
        for (int gg = 1; gg < 8; ++gg) {
            float4 t = colred[tid + 32 * gg];
            a.x += t.x; a.y += t.y; a.z += t.z; a.w += t.w;
        }
        float* dst = Scol8 + rep * DIM;              // ~128-way contention
        atomicAdd(&dst[4 * tid + 0], a.x);
        atomicAdd(&dst[4 * tid + 1], a.y);
        atomicAdd(&dst[4 * tid + 2], a.z);
        atomicAdd(&dst[4 * tid + 3], a.w);
    }
}

// ------- Kernel 2: per-class MFMA Gram hinge (8 blocks/class) + finalize ----
__global__ __launch_bounds__(256) void gram_kernel(
    const _Float16* __restrict__ gh, const float* __restrict__ sqg,
    const int* __restrict__ cnt,
    const float* __restrict__ Scol8, const float* __restrict__ SQc8,
    float* __restrict__ Hsum, float* __restrict__ SSsum,
    int* __restrict__ done, float* __restrict__ out)
{
    const int c = blockIdx.x >> 3, qq = blockIdx.x & 7, tid = threadIdx.x;
    __shared__ float wred[8];
    __shared__ int   lastFlag;

    const int mtrue = cnt[c];
    const int m = mtrue < CAP ? mtrue : CAP;
    const int ntiles = (m + 15) >> 4;
    const int ntp = ntiles * (ntiles + 1) / 2;       // ~21 for m~82

    const int wave = tid >> 6, lane = tid & 63;
    const int lr = lane & 15, q = lane >> 4;
    float hacc = 0.f, dsum = 0.f;
    const _Float16* base = gh + (size_t)c * CAP * DIM;
    const float* sqb_ = sqg + c * CAP;

    // 32 waves/class: almost always <=1 tile-pair per wave.
    for (int tp = qq * 4 + wave; tp < ntp; tp += 32) {
        int ta = 0, rem = tp;
        while (rem >= ntiles - ta) { rem -= ntiles - ta; ++ta; }
        const int tb = ta + rem;
        // Pad rows hold benign fp16 poison (no NaN/Inf); outputs gated below.
        const half8* ap = (const half8*)(base + (ta * 16 + lr) * DIM + q * 8);
        const half8* bp = (const half8*)(base + (tb * 16 + lr) * DIM + q * 8);
        float4v acc = {0.f, 0.f, 0.f, 0.f};
        #pragma unroll
        for (int kb = 0; kb < 4; ++kb)               // +32 halves per K block
            acc = __builtin_amdgcn_mfma_f32_16x16x32_f16(ap[kb * 4], bp[kb * 4], acc, 0, 0, 0);
        const float w = (ta == tb) ? 1.f : 2.f;
        const int bb = tb * 16 + lr;                 // C/D col = lane & 15
        const float sqb = (bb < m) ? sqb_[bb] : 0.f;
        #pragma unroll
        for (int i = 0; i < 4; ++i) {
            const int a = ta * 16 + q * 4 + i;       // C/D row = quad*4 + reg
            if (a < m && bb < m) {
                const float dot = acc[i];
                dsum += w * dot;                     // includes diagonal a==bb
                if (a != bb) {
                    float d = fmaxf(sqb_[a] + sqb - 2.f * dot, 0.f);
                    hacc += w * fmaxf(1.f - d, 0.f);
                }
            }
        }
    }
    #pragma unroll
    for (int off = 32; off > 0; off >>= 1) {
        hacc += __shfl_xor(hacc, off);
        dsum += __shfl_xor(dsum, off);
    }
    if (lane == 0) { wred[wave] = hacc; wred[4 + wave] = dsum; }
    __syncthreads();
    if (tid == 0) {
        float h = wred[0] + wred[1] + wred[2] + wred[3];
        float d = wred[4] + wred[5] + wred[6] + wred[7];
        if (h != 0.f) atomicAdd(Hsum, h);
        if (d != 0.f) atomicAdd(SSsum, d);
        __threadfence();                             // release before counting
        int p = atomicAdd(done, 1);
        lastFlag = (p == GRAMB - 1);
    }
    __syncthreads();
    if (!lastFlag) return;

    // ---------------- fused finalize (last-arriving block only) ------------
    __threadfence();                                 // acquire others' results
    const double Nf = (double)N_ROWS;
    double contrib = 0.0;
    if (tid < DIM) {                                 // -2 ||S||^2
        float sc = 0.f;
        #pragma unroll
        for (int k = 0; k < NREP; ++k) sc += Scol8[k * DIM + tid];
        contrib -= 2.0 * (double)sc * (double)sc;
    }
    if (tid < NCLS) {                                // 2 SQ_c (N - n_c)
        float qv = 0.f;
        #pragma unroll
        for (int k = 0; k < NREP; ++k) qv += SQc8[k * NCLS + tid];
        contrib += 2.0 * (double)qv * (Nf - (double)cnt[tid]);
    }
    if (tid == 0) {
        float H  = __hip_atomic_load(Hsum,  __ATOMIC_RELAXED, __HIP_MEMORY_SCOPE_AGENT);
        float SS = __hip_atomic_load(SSsum, __ATOMIC_RELAXED, __HIP_MEMORY_SCOPE_AGENT);
        contrib += 2.0 * (double)SS + (double)H + Nf * 1.0 /* N*margin */;
    }
    __shared__ double dred[256];
    dred[tid] = contrib;
    __syncthreads();
    for (int s = 128; s > 0; s >>= 1) {
        if (tid < s) dred[tid] += dred[tid + s];
        __syncthreads();
    }
    if (tid == 0) out[0] = (float)(dred[0] / (Nf * Nf));
}

extern "C" void kernel_launch(void* const* d_in, const int* in_sizes, int n_in,
                              void* d_out, int out_size, void* d_ws, size_t ws_size,
                              hipStream_t stream) {
    const float* x = (const float*)d_in[0];
    const int*   y = (const int*)d_in[1];

    _Float16* gh = (_Float16*)d_ws;                         // 100*224*128 fp16 = 5.73 MB
    float* sqg   = (float*)(gh + (size_t)NCLS * CAP * DIM); // 100*224
    int*   rank  = (int*)(sqg + NCLS * CAP);                // 8192
    // ---- zero region (single small memset): ----
    float* Scol8 = (float*)(rank + N_ROWS);  // NREP*128
    float* SQc8  = Scol8 + NREP * DIM;       // NREP*100
    float* Hsum  = SQc8 + NREP * NCLS;       // 1
    float* SSsum = Hsum + 1;                 // 1
    int*   cnt   = (int*)(SSsum + 1);        // 100
    int*   done  = cnt + NCLS;               // 1
    const size_t zero_words = NREP * DIM + NREP * NCLS + 2 + NCLS + 1; // 1927

    hipMemsetAsync(Scol8, 0, zero_words * sizeof(float), stream);
    rank_kernel<<<RB,    256, 0, stream>>>(y, cnt, rank);
    scan_kernel<<<SCB,   256, 0, stream>>>(x, y, rank, gh, sqg, Scol8, SQc8);
    gram_kernel<<<GRAMB, 256, 0, stream>>>(gh, sqg, cnt, Scol8, SQc8,
                                           Hsum, SSsum, done, (float*)d_out);
}